// Round 1
// baseline (2455.706 us; speedup 1.0000x reference)
//
#include <hip/hip_runtime.h>

#define BB 64
#define PP 100
#define NN 1000
#define DDIM 128
#define HH 8
#define NSPL 8

// ---------------------------------------------------------------------------
// proj: out[r][j] = scale * (beta*out[r][j] + bias[j] + sum_d x[r][d]*W[d][j])
// thread holds one W column in registers (persistent across grid-stride tiles);
// x reads are wave-uniform (compiler can scalarize / HW broadcasts).
// rows must be a multiple of 16.
// ---------------------------------------------------------------------------
__global__ __launch_bounds__(256) void proj_kernel(
    const float* __restrict__ x, const float* __restrict__ W,
    const float* __restrict__ bias, float* __restrict__ out,
    int rows, int beta, float scale)
{
  const int j = threadIdx.x & 127;
  const int half = threadIdx.x >> 7;   // 0 -> rows 0..7 of tile, 1 -> rows 8..15
  float w[DDIM];
#pragma unroll
  for (int d = 0; d < DDIM; ++d) w[d] = W[d * DDIM + j];
  const float bj = bias ? bias[j] : 0.0f;
  const int ntiles = rows >> 4;
  for (int tile = blockIdx.x; tile < ntiles; tile += gridDim.x) {
    const int r0 = tile * 16 + half * 8;
    const float* xr = x + r0 * DDIM;
    float acc[8];
#pragma unroll
    for (int i = 0; i < 8; ++i) acc[i] = bj;
#pragma unroll
    for (int dd4 = 0; dd4 < DDIM; dd4 += 4) {
#pragma unroll
      for (int i = 0; i < 8; ++i) {
        const float4 xv = *(const float4*)(xr + i * DDIM + dd4);
        acc[i] = fmaf(xv.x, w[dd4 + 0], acc[i]);
        acc[i] = fmaf(xv.y, w[dd4 + 1], acc[i]);
        acc[i] = fmaf(xv.z, w[dd4 + 2], acc[i]);
        acc[i] = fmaf(xv.w, w[dd4 + 3], acc[i]);
      }
    }
#pragma unroll
    for (int i = 0; i < 8; ++i) {
      float o = acc[i];
      if (beta) o += out[(r0 + i) * DDIM + j];
      out[(r0 + i) * DDIM + j] = o * scale;
    }
  }
}

// ---------------------------------------------------------------------------
// attention, split over N; no online max (scores statistically bounded << 88).
// thread = (p-pair, head). Writes un-normalized partials po = sum e*v and
// lsum = sum e per (b, split, p, h).
// grid = BB * NSPL, block = 448 (56 p-groups x 8 heads; pg<50 active)
// ---------------------------------------------------------------------------
__global__ __launch_bounds__(448) void attn_kernel(
    const float* __restrict__ Q, const float* __restrict__ K,
    const float* __restrict__ V, const float* __restrict__ mask,
    float* __restrict__ po, float* __restrict__ lsum)
{
  const int b = blockIdx.x >> 3;
  const int split = blockIdx.x & 7;
  const int t = threadIdx.x;
  const int pg = t >> 3;
  const int h = t & 7;
  const bool act = pg < 50;
  const int p0 = (act ? pg : 49) * 2;

  float q0[16], q1[16];
  const float* qp0 = Q + (b * PP + p0) * DDIM + h * 16;   // Q is pre-scaled by 0.25
#pragma unroll
  for (int c = 0; c < 4; ++c) {
    const float4 a = *(const float4*)(qp0 + 4 * c);
    const float4 bq = *(const float4*)(qp0 + DDIM + 4 * c);
    q0[4*c+0]=a.x;  q0[4*c+1]=a.y;  q0[4*c+2]=a.z;  q0[4*c+3]=a.w;
    q1[4*c+0]=bq.x; q1[4*c+1]=bq.y; q1[4*c+2]=bq.z; q1[4*c+3]=bq.w;
  }
  float a0[16], a1[16];
#pragma unroll
  for (int i = 0; i < 16; ++i) { a0[i] = 0.f; a1[i] = 0.f; }
  float l0 = 0.f, l1 = 0.f;

  const float* Kb = K + b * NN * DDIM + h * 16;
  const float* Vb = V + b * NN * DDIM + h * 16;
  const float* m0 = mask + (b * PP + p0) * NN;
  const float* m1 = m0 + NN;

  const int n0 = split * (NN / NSPL);
#pragma unroll 2
  for (int n = n0; n < n0 + NN / NSPL; ++n) {
    const float* kn = Kb + n * DDIM;
    float kr[16];
#pragma unroll
    for (int c = 0; c < 4; ++c) {
      const float4 kv = *(const float4*)(kn + 4 * c);
      kr[4*c+0]=kv.x; kr[4*c+1]=kv.y; kr[4*c+2]=kv.z; kr[4*c+3]=kv.w;
    }
    float s0a=0.f, s0b=0.f, s1a=0.f, s1b=0.f;
#pragma unroll
    for (int i = 0; i < 8; ++i) {
      s0a = fmaf(q0[i],   kr[i],   s0a);
      s0b = fmaf(q0[i+8], kr[i+8], s0b);
      s1a = fmaf(q1[i],   kr[i],   s1a);
      s1b = fmaf(q1[i+8], kr[i+8], s1b);
    }
    const float e0 = __expf((s0a + s0b) + m0[n]);
    const float e1 = __expf((s1a + s1b) + m1[n]);
    l0 += e0; l1 += e1;
    const float* vn = Vb + n * DDIM;
#pragma unroll
    for (int c = 0; c < 4; ++c) {
      const float4 vv = *(const float4*)(vn + 4 * c);
      a0[4*c+0] = fmaf(e0, vv.x, a0[4*c+0]);
      a0[4*c+1] = fmaf(e0, vv.y, a0[4*c+1]);
      a0[4*c+2] = fmaf(e0, vv.z, a0[4*c+2]);
      a0[4*c+3] = fmaf(e0, vv.w, a0[4*c+3]);
      a1[4*c+0] = fmaf(e1, vv.x, a1[4*c+0]);
      a1[4*c+1] = fmaf(e1, vv.y, a1[4*c+1]);
      a1[4*c+2] = fmaf(e1, vv.z, a1[4*c+2]);
      a1[4*c+3] = fmaf(e1, vv.w, a1[4*c+3]);
    }
  }
  if (act) {
    const int base = (b * NSPL + split) * PP + p0;
    float* d0 = po + base * DDIM + h * 16;
#pragma unroll
    for (int c = 0; c < 4; ++c) {
      *(float4*)(d0 + 4*c)        = make_float4(a0[4*c+0],a0[4*c+1],a0[4*c+2],a0[4*c+3]);
      *(float4*)(d0 + DDIM + 4*c) = make_float4(a1[4*c+0],a1[4*c+1],a1[4*c+2],a1[4*c+3]);
    }
    lsum[base * HH + h]       = l0;
    lsum[(base + 1) * HH + h] = l1;
  }
}

// ---------------------------------------------------------------------------
// merge: mh_in[b][p][d] = (sum_s po) / (sum_s lsum[h(d)])
// ---------------------------------------------------------------------------
__global__ __launch_bounds__(256) void merge_kernel(
    const float* __restrict__ po, const float* __restrict__ lsum,
    float* __restrict__ mh_in)
{
  const int idx = blockIdx.x * 256 + threadIdx.x;   // over BB*PP*DDIM
  const int d = idx & 127;
  const int row = idx >> 7;        // b*PP + p
  const int b = row / PP;
  const int p = row - b * PP;
  const int h = d >> 4;
  float s = 0.f, lt = 0.f;
#pragma unroll
  for (int sp = 0; sp < NSPL; ++sp) {
    const int base = (b * NSPL + sp) * PP + p;
    s  += po[base * DDIM + d];
    lt += lsum[base * HH + h];
  }
  mh_in[idx] = s / lt;
}

// ---------------------------------------------------------------------------
// score2 + bias + mask + exp  (softmax numerator; scores bounded by 10.2 so
// no max subtraction needed). Writes e to out, chunk-partial sums to ssum.
// grid = BB*4chunks*2phalf = 512, block = 256 (thread = one n; t<250 active)
// ---------------------------------------------------------------------------
__global__ __launch_bounds__(256) void score2_kernel(
    const float* __restrict__ enc, const float* __restrict__ mh,
    const float* __restrict__ mask, const float* __restrict__ bias_table,
    const int* __restrict__ group_ids, const int* __restrict__ cur_min,
    float* __restrict__ out, float* __restrict__ ssum)
{
  const int b = blockIdx.x >> 3;
  const int chunk = (blockIdx.x >> 1) & 3;
  const int phalf = blockIdx.x & 1;
  const int t = threadIdx.x;
  const int nn = chunk * 250 + t;
  const bool act = (t < 250);
  const int nc = act ? nn : chunk * 250;

  float er[DDIM];
  {
    const float* ep = enc + (b * NN + nc) * DDIM;
#pragma unroll
    for (int c = 0; c < 32; ++c) {
      const float4 v4 = *(const float4*)(ep + 4 * c);
      er[4*c+0]=v4.x; er[4*c+1]=v4.y; er[4*c+2]=v4.z; er[4*c+3]=v4.w;
    }
  }
  const int gid = group_ids[b * NN + nc];
  const float t0 = bias_table[0], t1 = bias_table[1], t2 = bias_table[2],
              t3 = bias_table[3], t4 = bias_table[4];

  __shared__ float psum[50];
  if (t < 50) psum[t] = 0.f;
  __syncthreads();

  const float inv_sqrt_emb = 0.08838834764831845f;  // 1/sqrt(128)
  const int p0 = phalf * 50;
  for (int pi = 0; pi < 50; ++pi) {
    const int p = p0 + pi;
    const float* mhp = mh + (b * PP + p) * DDIM;
    float d0=0.f, d1=0.f, d2=0.f, d3=0.f;
#pragma unroll
    for (int d = 0; d < DDIM; d += 4) {
      d0 = fmaf(er[d+0], mhp[d+0], d0);
      d1 = fmaf(er[d+1], mhp[d+1], d1);
      d2 = fmaf(er[d+2], mhp[d+2], d2);
      d3 = fmaf(er[d+3], mhp[d+3], d3);
    }
    const float dot = (d0 + d1) + (d2 + d3);
    // 10*tanh(x) = 10 - 20/(exp(2x)+1); saturates gracefully at +-10
    const float ex = __expf(dot * inv_sqrt_emb * 2.0f);
    const float sc = 10.0f - 20.0f / (ex + 1.0f);
    const int cmp = cur_min[b * PP + p];
    int delta = gid - cmp;
    delta = delta < 0 ? 0 : (delta > 4 ? 4 : delta);
    const float pb = (delta == 0) ? t0 : (delta == 1) ? t1 : (delta == 2) ? t2
                   : (delta == 3) ? t3 : t4;
    const float m = mask[(b * PP + p) * NN + nc];
    const float e = act ? __expf(sc + pb + m) : 0.0f;   // exp(-inf)=0 handles mask
    if (act) out[(b * PP + p) * NN + nn] = e;
    float wsum = e;
#pragma unroll
    for (int off = 1; off < 64; off <<= 1) wsum += __shfl_xor(wsum, off, 64);
    if ((t & 63) == 0) atomicAdd(&psum[pi], wsum);
  }
  __syncthreads();
  if (t < 50) ssum[(b * PP + p0 + t) * 4 + chunk] = psum[t];
}

// ---------------------------------------------------------------------------
// normalize: out[row][n] /= sum of 4 chunk partials
// ---------------------------------------------------------------------------
__global__ __launch_bounds__(256) void norm_kernel(
    const float* __restrict__ ssum, float* __restrict__ out)
{
  const int row = blockIdx.x;   // b*PP + p
  const float s = ssum[row*4+0] + ssum[row*4+1] + ssum[row*4+2] + ssum[row*4+3];
  const float inv = 1.0f / s;
#pragma unroll
  for (int i = 0; i < 4; ++i) {
    const int c = i * 256 + (int)threadIdx.x;
    if (c < NN) out[row * NN + c] *= inv;
  }
}

// ---------------------------------------------------------------------------
extern "C" void kernel_launch(void* const* d_in, const int* in_sizes, int n_in,
                              void* d_out, int out_size, void* d_ws, size_t ws_size,
                              hipStream_t stream)
{
  (void)in_sizes; (void)n_in; (void)out_size; (void)ws_size;
  const float* enc_nodes  = (const float*)d_in[0];
  const float* enc_q1     = (const float*)d_in[1];
  const float* enc_last   = (const float*)d_in[2];
  const float* ninf       = (const float*)d_in[3];
  const float* Wq_first   = (const float*)d_in[4];
  const float* Wq_last    = (const float*)d_in[5];
  const float* Wk         = (const float*)d_in[6];
  const float* Wv         = (const float*)d_in[7];
  const float* W_comb     = (const float*)d_in[8];
  const float* b_comb     = (const float*)d_in[9];
  const float* bias_table = (const float*)d_in[10];
  const int*   group_ids  = (const int*)d_in[11];
  const int*   cur_min    = (const int*)d_in[12];
  float* out = (float*)d_out;
  float* ws  = (float*)d_ws;

  float* Qw = ws;                    //   819200 floats (reused as mh_in after attn)
  float* Kw = Qw + 819200;           //  8192000
  float* Vw = Kw + 8192000;          //  8192000
  float* po = Vw + 8192000;          //  6553600  (BB*NSPL*PP*DDIM)
  float* ls = po + 6553600;          //   409600  (BB*NSPL*PP*HH)
  float* mh = ls + 409600;           //   819200
  float* sm = mh + 819200;           //    25600  (BB*PP*4)

  // Q = (q1@Wq_first + last@Wq_last) * 0.25  (fold 1/sqrt(QD))
  proj_kernel<<<400, 256, 0, stream>>>(enc_q1,   Wq_first, nullptr, Qw, BB*PP, 0, 1.0f);
  proj_kernel<<<400, 256, 0, stream>>>(enc_last, Wq_last,  nullptr, Qw, BB*PP, 1, 0.25f);
  // K, V projections
  proj_kernel<<<2048, 256, 0, stream>>>(enc_nodes, Wk, nullptr, Kw, BB*NN, 0, 1.0f);
  proj_kernel<<<2048, 256, 0, stream>>>(enc_nodes, Wv, nullptr, Vw, BB*NN, 0, 1.0f);
  // attention partials
  attn_kernel<<<BB*NSPL, 448, 0, stream>>>(Qw, Kw, Vw, ninf, po, ls);
  // merge partials -> mh_in (reuses Qw)
  merge_kernel<<<3200, 256, 0, stream>>>(po, ls, Qw);
  // combine: mh = mh_in @ W_comb + b_comb
  proj_kernel<<<400, 256, 0, stream>>>(Qw, W_comb, b_comb, mh, BB*PP, 0, 1.0f);
  // final scores + exp + partial sums
  score2_kernel<<<BB*8, 256, 0, stream>>>(enc_nodes, mh, ninf, bias_table,
                                          group_ids, cur_min, out, sm);
  // normalize
  norm_kernel<<<BB*PP, 256, 0, stream>>>(sm, out);
}

// Round 2
// 585.616 us; speedup vs baseline: 4.1934x; 4.1934x over previous
//
#include <hip/hip_runtime.h>

#define BB 64
#define PP 100
#define NN 1000
#define DDIM 128
#define HH 8
#define NSPL 8

// ---------------------------------------------------------------------------
// Fused K+V projection: outa = x@Wa, outb = x@Wb.
// W streamed in 8-deep chunks (unroll 2 -> 16-deep) instead of 128 persistent
// registers -- round-1 version spilled (VGPR=256, 1.6GB scratch writes).
// Thread = one output column j, 8 rows; block tile = 16 rows x 128 cols.
// ---------------------------------------------------------------------------
__global__ __launch_bounds__(256) void proj_kv_kernel(
    const float* __restrict__ x, const float* __restrict__ Wa,
    const float* __restrict__ Wb, float* __restrict__ outa,
    float* __restrict__ outb, int rows)
{
  const int j = threadIdx.x & 127;
  const int half = threadIdx.x >> 7;
  const int ntiles = rows >> 4;
  for (int tile = blockIdx.x; tile < ntiles; tile += gridDim.x) {
    const int r0 = tile * 16 + half * 8;
    const float* xr = x + r0 * DDIM;
    float acca[8], accb[8];
#pragma unroll
    for (int i = 0; i < 8; ++i) { acca[i] = 0.f; accb[i] = 0.f; }
#pragma unroll 2
    for (int dc = 0; dc < DDIM; dc += 8) {
      float wa[8], wb[8];
#pragma unroll
      for (int u = 0; u < 8; ++u) {
        wa[u] = Wa[(dc + u) * DDIM + j];
        wb[u] = Wb[(dc + u) * DDIM + j];
      }
#pragma unroll
      for (int i = 0; i < 8; ++i) {
        const float4 x0 = *(const float4*)(xr + i * DDIM + dc);
        const float4 x1 = *(const float4*)(xr + i * DDIM + dc + 4);
        acca[i] = fmaf(x0.x, wa[0], acca[i]);
        acca[i] = fmaf(x0.y, wa[1], acca[i]);
        acca[i] = fmaf(x0.z, wa[2], acca[i]);
        acca[i] = fmaf(x0.w, wa[3], acca[i]);
        acca[i] = fmaf(x1.x, wa[4], acca[i]);
        acca[i] = fmaf(x1.y, wa[5], acca[i]);
        acca[i] = fmaf(x1.z, wa[6], acca[i]);
        acca[i] = fmaf(x1.w, wa[7], acca[i]);
        accb[i] = fmaf(x0.x, wb[0], accb[i]);
        accb[i] = fmaf(x0.y, wb[1], accb[i]);
        accb[i] = fmaf(x0.z, wb[2], accb[i]);
        accb[i] = fmaf(x0.w, wb[3], accb[i]);
        accb[i] = fmaf(x1.x, wb[4], accb[i]);
        accb[i] = fmaf(x1.y, wb[5], accb[i]);
        accb[i] = fmaf(x1.z, wb[6], accb[i]);
        accb[i] = fmaf(x1.w, wb[7], accb[i]);
      }
    }
#pragma unroll
    for (int i = 0; i < 8; ++i) {
      outa[(r0 + i) * DDIM + j] = acca[i];
      outb[(r0 + i) * DDIM + j] = accb[i];
    }
  }
}

// ---------------------------------------------------------------------------
// Fused Q projection: out = (x1@W1 + x2@W2) * scale   (scale folds 1/sqrt(QD))
// ---------------------------------------------------------------------------
__global__ __launch_bounds__(256) void proj_q2_kernel(
    const float* __restrict__ x1, const float* __restrict__ x2,
    const float* __restrict__ W1, const float* __restrict__ W2,
    float* __restrict__ out, int rows, float scale)
{
  const int j = threadIdx.x & 127;
  const int half = threadIdx.x >> 7;
  const int ntiles = rows >> 4;
  for (int tile = blockIdx.x; tile < ntiles; tile += gridDim.x) {
    const int r0 = tile * 16 + half * 8;
    const float* xr1 = x1 + r0 * DDIM;
    const float* xr2 = x2 + r0 * DDIM;
    float acc[8];
#pragma unroll
    for (int i = 0; i < 8; ++i) acc[i] = 0.f;
#pragma unroll 2
    for (int dc = 0; dc < DDIM; dc += 8) {
      float w1[8], w2[8];
#pragma unroll
      for (int u = 0; u < 8; ++u) {
        w1[u] = W1[(dc + u) * DDIM + j];
        w2[u] = W2[(dc + u) * DDIM + j];
      }
#pragma unroll
      for (int i = 0; i < 8; ++i) {
        const float4 a0 = *(const float4*)(xr1 + i * DDIM + dc);
        const float4 a1 = *(const float4*)(xr1 + i * DDIM + dc + 4);
        acc[i] = fmaf(a0.x, w1[0], acc[i]);
        acc[i] = fmaf(a0.y, w1[1], acc[i]);
        acc[i] = fmaf(a0.z, w1[2], acc[i]);
        acc[i] = fmaf(a0.w, w1[3], acc[i]);
        acc[i] = fmaf(a1.x, w1[4], acc[i]);
        acc[i] = fmaf(a1.y, w1[5], acc[i]);
        acc[i] = fmaf(a1.z, w1[6], acc[i]);
        acc[i] = fmaf(a1.w, w1[7], acc[i]);
        const float4 b0 = *(const float4*)(xr2 + i * DDIM + dc);
        const float4 b1 = *(const float4*)(xr2 + i * DDIM + dc + 4);
        acc[i] = fmaf(b0.x, w2[0], acc[i]);
        acc[i] = fmaf(b0.y, w2[1], acc[i]);
        acc[i] = fmaf(b0.z, w2[2], acc[i]);
        acc[i] = fmaf(b0.w, w2[3], acc[i]);
        acc[i] = fmaf(b1.x, w2[4], acc[i]);
        acc[i] = fmaf(b1.y, w2[5], acc[i]);
        acc[i] = fmaf(b1.z, w2[6], acc[i]);
        acc[i] = fmaf(b1.w, w2[7], acc[i]);
      }
    }
#pragma unroll
    for (int i = 0; i < 8; ++i)
      out[(r0 + i) * DDIM + j] = acc[i] * scale;
  }
}

// ---------------------------------------------------------------------------
// Single proj with bias (combine layer): out = x@W + bias
// ---------------------------------------------------------------------------
__global__ __launch_bounds__(256) void proj_bias_kernel(
    const float* __restrict__ x, const float* __restrict__ W,
    const float* __restrict__ bias, float* __restrict__ out, int rows)
{
  const int j = threadIdx.x & 127;
  const int half = threadIdx.x >> 7;
  const float bj = bias[j];
  const int ntiles = rows >> 4;
  for (int tile = blockIdx.x; tile < ntiles; tile += gridDim.x) {
    const int r0 = tile * 16 + half * 8;
    const float* xr = x + r0 * DDIM;
    float acc[8];
#pragma unroll
    for (int i = 0; i < 8; ++i) acc[i] = bj;
#pragma unroll 2
    for (int dc = 0; dc < DDIM; dc += 8) {
      float w[8];
#pragma unroll
      for (int u = 0; u < 8; ++u) w[u] = W[(dc + u) * DDIM + j];
#pragma unroll
      for (int i = 0; i < 8; ++i) {
        const float4 x0 = *(const float4*)(xr + i * DDIM + dc);
        const float4 x1 = *(const float4*)(xr + i * DDIM + dc + 4);
        acc[i] = fmaf(x0.x, w[0], acc[i]);
        acc[i] = fmaf(x0.y, w[1], acc[i]);
        acc[i] = fmaf(x0.z, w[2], acc[i]);
        acc[i] = fmaf(x0.w, w[3], acc[i]);
        acc[i] = fmaf(x1.x, w[4], acc[i]);
        acc[i] = fmaf(x1.y, w[5], acc[i]);
        acc[i] = fmaf(x1.z, w[6], acc[i]);
        acc[i] = fmaf(x1.w, w[7], acc[i]);
      }
    }
#pragma unroll
    for (int i = 0; i < 8; ++i)
      out[(r0 + i) * DDIM + j] = acc[i];
  }
}

// ---------------------------------------------------------------------------
// attention, split over N; no online max (scores statistically bounded << 88).
// thread = (p-pair, head). Writes un-normalized partials po = sum e*v and
// lsum = sum e per (b, split, p, h).
// grid = BB * NSPL, block = 448 (56 p-groups x 8 heads; pg<50 active)
// ---------------------------------------------------------------------------
__global__ __launch_bounds__(448) void attn_kernel(
    const float* __restrict__ Q, const float* __restrict__ K,
    const float* __restrict__ V, const float* __restrict__ mask,
    float* __restrict__ po, float* __restrict__ lsum)
{
  const int b = blockIdx.x >> 3;
  const int split = blockIdx.x & 7;
  const int t = threadIdx.x;
  const int pg = t >> 3;
  const int h = t & 7;
  const bool act = pg < 50;
  const int p0 = (act ? pg : 49) * 2;

  float q0[16], q1[16];
  const float* qp0 = Q + (b * PP + p0) * DDIM + h * 16;   // Q is pre-scaled by 0.25
#pragma unroll
  for (int c = 0; c < 4; ++c) {
    const float4 a = *(const float4*)(qp0 + 4 * c);
    const float4 bq = *(const float4*)(qp0 + DDIM + 4 * c);
    q0[4*c+0]=a.x;  q0[4*c+1]=a.y;  q0[4*c+2]=a.z;  q0[4*c+3]=a.w;
    q1[4*c+0]=bq.x; q1[4*c+1]=bq.y; q1[4*c+2]=bq.z; q1[4*c+3]=bq.w;
  }
  float a0[16], a1[16];
#pragma unroll
  for (int i = 0; i < 16; ++i) { a0[i] = 0.f; a1[i] = 0.f; }
  float l0 = 0.f, l1 = 0.f;

  const float* Kb = K + b * NN * DDIM + h * 16;
  const float* Vb = V + b * NN * DDIM + h * 16;
  const float* m0 = mask + (b * PP + p0) * NN;
  const float* m1 = m0 + NN;

  const int n0 = split * (NN / NSPL);
#pragma unroll 2
  for (int n = n0; n < n0 + NN / NSPL; ++n) {
    const float* kn = Kb + n * DDIM;
    float kr[16];
#pragma unroll
    for (int c = 0; c < 4; ++c) {
      const float4 kv = *(const float4*)(kn + 4 * c);
      kr[4*c+0]=kv.x; kr[4*c+1]=kv.y; kr[4*c+2]=kv.z; kr[4*c+3]=kv.w;
    }
    float s0a=0.f, s0b=0.f, s1a=0.f, s1b=0.f;
#pragma unroll
    for (int i = 0; i < 8; ++i) {
      s0a = fmaf(q0[i],   kr[i],   s0a);
      s0b = fmaf(q0[i+8], kr[i+8], s0b);
      s1a = fmaf(q1[i],   kr[i],   s1a);
      s1b = fmaf(q1[i+8], kr[i+8], s1b);
    }
    const float e0 = __expf((s0a + s0b) + m0[n]);
    const float e1 = __expf((s1a + s1b) + m1[n]);
    l0 += e0; l1 += e1;
    const float* vn = Vb + n * DDIM;
#pragma unroll
    for (int c = 0; c < 4; ++c) {
      const float4 vv = *(const float4*)(vn + 4 * c);
      a0[4*c+0] = fmaf(e0, vv.x, a0[4*c+0]);
      a0[4*c+1] = fmaf(e0, vv.y, a0[4*c+1]);
      a0[4*c+2] = fmaf(e0, vv.z, a0[4*c+2]);
      a0[4*c+3] = fmaf(e0, vv.w, a0[4*c+3]);
      a1[4*c+0] = fmaf(e1, vv.x, a1[4*c+0]);
      a1[4*c+1] = fmaf(e1, vv.y, a1[4*c+1]);
      a1[4*c+2] = fmaf(e1, vv.z, a1[4*c+2]);
      a1[4*c+3] = fmaf(e1, vv.w, a1[4*c+3]);
    }
  }
  if (act) {
    const int base = (b * NSPL + split) * PP + p0;
    float* d0 = po + base * DDIM + h * 16;
#pragma unroll
    for (int c = 0; c < 4; ++c) {
      *(float4*)(d0 + 4*c)        = make_float4(a0[4*c+0],a0[4*c+1],a0[4*c+2],a0[4*c+3]);
      *(float4*)(d0 + DDIM + 4*c) = make_float4(a1[4*c+0],a1[4*c+1],a1[4*c+2],a1[4*c+3]);
    }
    lsum[base * HH + h]       = l0;
    lsum[(base + 1) * HH + h] = l1;
  }
}

// ---------------------------------------------------------------------------
// merge: mh_in[b][p][d] = (sum_s po) / (sum_s lsum[h(d)])
// ---------------------------------------------------------------------------
__global__ __launch_bounds__(256) void merge_kernel(
    const float* __restrict__ po, const float* __restrict__ lsum,
    float* __restrict__ mh_in)
{
  const int idx = blockIdx.x * 256 + threadIdx.x;   // over BB*PP*DDIM
  const int d = idx & 127;
  const int row = idx >> 7;        // b*PP + p
  const int b = row / PP;
  const int p = row - b * PP;
  const int h = d >> 4;
  float s = 0.f, lt = 0.f;
#pragma unroll
  for (int sp = 0; sp < NSPL; ++sp) {
    const int base = (b * NSPL + sp) * PP + p;
    s  += po[base * DDIM + d];
    lt += lsum[base * HH + h];
  }
  mh_in[idx] = s / lt;
}

// ---------------------------------------------------------------------------
// score2 + bias + mask + exp  (softmax numerator; scores bounded by 10.2 so
// no max subtraction needed). Writes e to out, chunk-partial sums to ssum.
// grid = BB*4chunks*2phalf = 512, block = 256 (thread = one n; t<250 active)
// ---------------------------------------------------------------------------
__global__ __launch_bounds__(256) void score2_kernel(
    const float* __restrict__ enc, const float* __restrict__ mh,
    const float* __restrict__ mask, const float* __restrict__ bias_table,
    const int* __restrict__ group_ids, const int* __restrict__ cur_min,
    float* __restrict__ out, float* __restrict__ ssum)
{
  const int b = blockIdx.x >> 3;
  const int chunk = (blockIdx.x >> 1) & 3;
  const int phalf = blockIdx.x & 1;
  const int t = threadIdx.x;
  const int nn = chunk * 250 + t;
  const bool act = (t < 250);
  const int nc = act ? nn : chunk * 250;

  float er[DDIM];
  {
    const float* ep = enc + (b * NN + nc) * DDIM;
#pragma unroll
    for (int c = 0; c < 32; ++c) {
      const float4 v4 = *(const float4*)(ep + 4 * c);
      er[4*c+0]=v4.x; er[4*c+1]=v4.y; er[4*c+2]=v4.z; er[4*c+3]=v4.w;
    }
  }
  const int gid = group_ids[b * NN + nc];
  const float t0 = bias_table[0], t1 = bias_table[1], t2 = bias_table[2],
              t3 = bias_table[3], t4 = bias_table[4];

  __shared__ float psum[50];
  if (t < 50) psum[t] = 0.f;
  __syncthreads();

  const float inv_sqrt_emb = 0.08838834764831845f;  // 1/sqrt(128)
  const int p0 = phalf * 50;
  for (int pi = 0; pi < 50; ++pi) {
    const int p = p0 + pi;
    const float* mhp = mh + (b * PP + p) * DDIM;
    float d0=0.f, d1=0.f, d2=0.f, d3=0.f;
#pragma unroll
    for (int d = 0; d < DDIM; d += 4) {
      d0 = fmaf(er[d+0], mhp[d+0], d0);
      d1 = fmaf(er[d+1], mhp[d+1], d1);
      d2 = fmaf(er[d+2], mhp[d+2], d2);
      d3 = fmaf(er[d+3], mhp[d+3], d3);
    }
    const float dot = (d0 + d1) + (d2 + d3);
    // 10*tanh(x) = 10 - 20/(exp(2x)+1); saturates gracefully at +-10
    const float ex = __expf(dot * inv_sqrt_emb * 2.0f);
    const float sc = 10.0f - 20.0f / (ex + 1.0f);
    const int cmp = cur_min[b * PP + p];
    int delta = gid - cmp;
    delta = delta < 0 ? 0 : (delta > 4 ? 4 : delta);
    const float pb = (delta == 0) ? t0 : (delta == 1) ? t1 : (delta == 2) ? t2
                   : (delta == 3) ? t3 : t4;
    const float m = mask[(b * PP + p) * NN + nc];
    const float e = act ? __expf(sc + pb + m) : 0.0f;   // exp(-inf)=0 handles mask
    if (act) out[(b * PP + p) * NN + nn] = e;
    float wsum = e;
#pragma unroll
    for (int off = 1; off < 64; off <<= 1) wsum += __shfl_xor(wsum, off, 64);
    if ((t & 63) == 0) atomicAdd(&psum[pi], wsum);
  }
  __syncthreads();
  if (t < 50) ssum[(b * PP + p0 + t) * 4 + chunk] = psum[t];
}

// ---------------------------------------------------------------------------
// normalize: out[row][n] /= sum of 4 chunk partials
// ---------------------------------------------------------------------------
__global__ __launch_bounds__(256) void norm_kernel(
    const float* __restrict__ ssum, float* __restrict__ out)
{
  const int row = blockIdx.x;   // b*PP + p
  const float s = ssum[row*4+0] + ssum[row*4+1] + ssum[row*4+2] + ssum[row*4+3];
  const float inv = 1.0f / s;
#pragma unroll
  for (int i = 0; i < 4; ++i) {
    const int c = i * 256 + (int)threadIdx.x;
    if (c < NN) out[row * NN + c] *= inv;
  }
}

// ---------------------------------------------------------------------------
extern "C" void kernel_launch(void* const* d_in, const int* in_sizes, int n_in,
                              void* d_out, int out_size, void* d_ws, size_t ws_size,
                              hipStream_t stream)
{
  (void)in_sizes; (void)n_in; (void)out_size; (void)ws_size;
  const float* enc_nodes  = (const float*)d_in[0];
  const float* enc_q1     = (const float*)d_in[1];
  const float* enc_last   = (const float*)d_in[2];
  const float* ninf       = (const float*)d_in[3];
  const float* Wq_first   = (const float*)d_in[4];
  const float* Wq_last    = (const float*)d_in[5];
  const float* Wk         = (const float*)d_in[6];
  const float* Wv         = (const float*)d_in[7];
  const float* W_comb     = (const float*)d_in[8];
  const float* b_comb     = (const float*)d_in[9];
  const float* bias_table = (const float*)d_in[10];
  const int*   group_ids  = (const int*)d_in[11];
  const int*   cur_min    = (const int*)d_in[12];
  float* out = (float*)d_out;
  float* ws  = (float*)d_ws;

  float* Qw = ws;                    //   819200 floats (reused as mh_in after attn)
  float* Kw = Qw + 819200;           //  8192000
  float* Vw = Kw + 8192000;          //  8192000
  float* po = Vw + 8192000;          //  6553600  (BB*NSPL*PP*DDIM)
  float* ls = po + 6553600;          //   409600  (BB*NSPL*PP*HH)
  float* mh = ls + 409600;           //   819200
  float* sm = mh + 819200;           //    25600  (BB*PP*4)

  // Q = (q1@Wq_first + last@Wq_last) * 0.25  (fold 1/sqrt(QD))
  proj_q2_kernel<<<400, 256, 0, stream>>>(enc_q1, enc_last, Wq_first, Wq_last,
                                          Qw, BB*PP, 0.25f);
  // K, V projections fused (one pass over enc_nodes)
  proj_kv_kernel<<<2000, 256, 0, stream>>>(enc_nodes, Wk, Wv, Kw, Vw, BB*NN);
  // attention partials
  attn_kernel<<<BB*NSPL, 448, 0, stream>>>(Qw, Kw, Vw, ninf, po, ls);
  // merge partials -> mh_in (reuses Qw)
  merge_kernel<<<3200, 256, 0, stream>>>(po, ls, Qw);
  // combine: mh = mh_in @ W_comb + b_comb
  proj_bias_kernel<<<400, 256, 0, stream>>>(Qw, W_comb, b_comb, mh, BB*PP);
  // final scores + exp + partial sums
  score2_kernel<<<BB*8, 256, 0, stream>>>(enc_nodes, mh, ninf, bias_table,
                                          group_ids, cur_min, out, sm);
  // normalize
  norm_kernel<<<BB*PP, 256, 0, stream>>>(sm, out);
}

// Round 3
// 452.524 us; speedup vs baseline: 5.4267x; 1.2941x over previous
//
#include <hip/hip_runtime.h>

#define BB 64
#define PP 100
#define NN 1000
#define DDIM 128
#define HH 8
#define NSPL 8
#define TN 25   // K/V rows staged in LDS per chunk (125 = 5 * 25 per split)

// ---------------------------------------------------------------------------
// Fused K+V projection: outa = x@Wa, outb = x@Wb.
// W streamed in 8-deep chunks; thread = column j, 8 rows.
// ---------------------------------------------------------------------------
__global__ __launch_bounds__(256) void proj_kv_kernel(
    const float* __restrict__ x, const float* __restrict__ Wa,
    const float* __restrict__ Wb, float* __restrict__ outa,
    float* __restrict__ outb, int rows)
{
  const int j = threadIdx.x & 127;
  const int half = threadIdx.x >> 7;
  const int ntiles = rows >> 4;
  for (int tile = blockIdx.x; tile < ntiles; tile += gridDim.x) {
    const int r0 = tile * 16 + half * 8;
    const float* xr = x + r0 * DDIM;
    float acca[8], accb[8];
#pragma unroll
    for (int i = 0; i < 8; ++i) { acca[i] = 0.f; accb[i] = 0.f; }
#pragma unroll 2
    for (int dc = 0; dc < DDIM; dc += 8) {
      float wa[8], wb[8];
#pragma unroll
      for (int u = 0; u < 8; ++u) {
        wa[u] = Wa[(dc + u) * DDIM + j];
        wb[u] = Wb[(dc + u) * DDIM + j];
      }
#pragma unroll
      for (int i = 0; i < 8; ++i) {
        const float4 x0 = *(const float4*)(xr + i * DDIM + dc);
        const float4 x1 = *(const float4*)(xr + i * DDIM + dc + 4);
        acca[i] = fmaf(x0.x, wa[0], acca[i]);
        acca[i] = fmaf(x0.y, wa[1], acca[i]);
        acca[i] = fmaf(x0.z, wa[2], acca[i]);
        acca[i] = fmaf(x0.w, wa[3], acca[i]);
        acca[i] = fmaf(x1.x, wa[4], acca[i]);
        acca[i] = fmaf(x1.y, wa[5], acca[i]);
        acca[i] = fmaf(x1.z, wa[6], acca[i]);
        acca[i] = fmaf(x1.w, wa[7], acca[i]);
        accb[i] = fmaf(x0.x, wb[0], accb[i]);
        accb[i] = fmaf(x0.y, wb[1], accb[i]);
        accb[i] = fmaf(x0.z, wb[2], accb[i]);
        accb[i] = fmaf(x0.w, wb[3], accb[i]);
        accb[i] = fmaf(x1.x, wb[4], accb[i]);
        accb[i] = fmaf(x1.y, wb[5], accb[i]);
        accb[i] = fmaf(x1.z, wb[6], accb[i]);
        accb[i] = fmaf(x1.w, wb[7], accb[i]);
      }
    }
#pragma unroll
    for (int i = 0; i < 8; ++i) {
      outa[(r0 + i) * DDIM + j] = acca[i];
      outb[(r0 + i) * DDIM + j] = accb[i];
    }
  }
}

// ---------------------------------------------------------------------------
// Fused Q projection: out = (x1@W1 + x2@W2) * scale   (scale folds 1/sqrt(QD))
// ---------------------------------------------------------------------------
__global__ __launch_bounds__(256) void proj_q2_kernel(
    const float* __restrict__ x1, const float* __restrict__ x2,
    const float* __restrict__ W1, const float* __restrict__ W2,
    float* __restrict__ out, int rows, float scale)
{
  const int j = threadIdx.x & 127;
  const int half = threadIdx.x >> 7;
  const int ntiles = rows >> 4;
  for (int tile = blockIdx.x; tile < ntiles; tile += gridDim.x) {
    const int r0 = tile * 16 + half * 8;
    const float* xr1 = x1 + r0 * DDIM;
    const float* xr2 = x2 + r0 * DDIM;
    float acc[8];
#pragma unroll
    for (int i = 0; i < 8; ++i) acc[i] = 0.f;
#pragma unroll 2
    for (int dc = 0; dc < DDIM; dc += 8) {
      float w1[8], w2[8];
#pragma unroll
      for (int u = 0; u < 8; ++u) {
        w1[u] = W1[(dc + u) * DDIM + j];
        w2[u] = W2[(dc + u) * DDIM + j];
      }
#pragma unroll
      for (int i = 0; i < 8; ++i) {
        const float4 a0 = *(const float4*)(xr1 + i * DDIM + dc);
        const float4 a1 = *(const float4*)(xr1 + i * DDIM + dc + 4);
        acc[i] = fmaf(a0.x, w1[0], acc[i]);
        acc[i] = fmaf(a0.y, w1[1], acc[i]);
        acc[i] = fmaf(a0.z, w1[2], acc[i]);
        acc[i] = fmaf(a0.w, w1[3], acc[i]);
        acc[i] = fmaf(a1.x, w1[4], acc[i]);
        acc[i] = fmaf(a1.y, w1[5], acc[i]);
        acc[i] = fmaf(a1.z, w1[6], acc[i]);
        acc[i] = fmaf(a1.w, w1[7], acc[i]);
        const float4 b0 = *(const float4*)(xr2 + i * DDIM + dc);
        const float4 b1 = *(const float4*)(xr2 + i * DDIM + dc + 4);
        acc[i] = fmaf(b0.x, w2[0], acc[i]);
        acc[i] = fmaf(b0.y, w2[1], acc[i]);
        acc[i] = fmaf(b0.z, w2[2], acc[i]);
        acc[i] = fmaf(b0.w, w2[3], acc[i]);
        acc[i] = fmaf(b1.x, w2[4], acc[i]);
        acc[i] = fmaf(b1.y, w2[5], acc[i]);
        acc[i] = fmaf(b1.z, w2[6], acc[i]);
        acc[i] = fmaf(b1.w, w2[7], acc[i]);
      }
    }
#pragma unroll
    for (int i = 0; i < 8; ++i)
      out[(r0 + i) * DDIM + j] = acc[i] * scale;
  }
}

// ---------------------------------------------------------------------------
// Single proj with bias (combine layer): out = x@W + bias
// ---------------------------------------------------------------------------
__global__ __launch_bounds__(256) void proj_bias_kernel(
    const float* __restrict__ x, const float* __restrict__ W,
    const float* __restrict__ bias, float* __restrict__ out, int rows)
{
  const int j = threadIdx.x & 127;
  const int half = threadIdx.x >> 7;
  const float bj = bias[j];
  const int ntiles = rows >> 4;
  for (int tile = blockIdx.x; tile < ntiles; tile += gridDim.x) {
    const int r0 = tile * 16 + half * 8;
    const float* xr = x + r0 * DDIM;
    float acc[8];
#pragma unroll
    for (int i = 0; i < 8; ++i) acc[i] = bj;
#pragma unroll 2
    for (int dc = 0; dc < DDIM; dc += 8) {
      float w[8];
#pragma unroll
      for (int u = 0; u < 8; ++u) w[u] = W[(dc + u) * DDIM + j];
#pragma unroll
      for (int i = 0; i < 8; ++i) {
        const float4 x0 = *(const float4*)(xr + i * DDIM + dc);
        const float4 x1 = *(const float4*)(xr + i * DDIM + dc + 4);
        acc[i] = fmaf(x0.x, w[0], acc[i]);
        acc[i] = fmaf(x0.y, w[1], acc[i]);
        acc[i] = fmaf(x0.z, w[2], acc[i]);
        acc[i] = fmaf(x0.w, w[3], acc[i]);
        acc[i] = fmaf(x1.x, w[4], acc[i]);
        acc[i] = fmaf(x1.y, w[5], acc[i]);
        acc[i] = fmaf(x1.z, w[6], acc[i]);
        acc[i] = fmaf(x1.w, w[7], acc[i]);
      }
    }
#pragma unroll
    for (int i = 0; i < 8; ++i)
      out[(r0 + i) * DDIM + j] = acc[i];
  }
}

// ---------------------------------------------------------------------------
// attention, split over N, K/V staged in LDS (round-2 version was VMEM-issue
// bound: 50 p-groups re-read the same K/V rows from L1, VALUBusy 19%).
// LDS broadcast serves the 8-way h duplication and 50-way p reuse for free.
// thread = (p-pair, head). grid = BB*NSPL, block = 448 (pg<50 active).
// ---------------------------------------------------------------------------
__global__ __launch_bounds__(448) void attn_kernel(
    const float* __restrict__ Q, const float* __restrict__ K,
    const float* __restrict__ V, const float* __restrict__ mask,
    float* __restrict__ po, float* __restrict__ lsum)
{
  __shared__ float Ks[TN * DDIM];
  __shared__ float Vs[TN * DDIM];

  const int b = blockIdx.x >> 3;
  const int split = blockIdx.x & 7;
  const int t = threadIdx.x;
  const int pg = t >> 3;
  const int h = t & 7;
  const bool act = pg < 50;
  const int p0 = (act ? pg : 49) * 2;

  float q0[16], q1[16];
  const float* qp0 = Q + (b * PP + p0) * DDIM + h * 16;   // Q pre-scaled by 0.25
#pragma unroll
  for (int c = 0; c < 4; ++c) {
    const float4 a = *(const float4*)(qp0 + 4 * c);
    const float4 bq = *(const float4*)(qp0 + DDIM + 4 * c);
    q0[4*c+0]=a.x;  q0[4*c+1]=a.y;  q0[4*c+2]=a.z;  q0[4*c+3]=a.w;
    q1[4*c+0]=bq.x; q1[4*c+1]=bq.y; q1[4*c+2]=bq.z; q1[4*c+3]=bq.w;
  }
  float a0[16], a1[16];
#pragma unroll
  for (int i = 0; i < 16; ++i) { a0[i] = 0.f; a1[i] = 0.f; }
  float l0 = 0.f, l1 = 0.f;

  const float* m0 = mask + (b * PP + p0) * NN;
  const float* m1 = m0 + NN;

  const int n0 = split * (NN / NSPL);           // 125 n per split
  for (int c0 = 0; c0 < NN / NSPL; c0 += TN) {  // 5 chunks of 25
    __syncthreads();                            // prev chunk fully consumed
    for (int idx = t; idx < TN * 32; idx += 448) {
      const int row = idx >> 5;
      const int col = (idx & 31) * 4;
      const int g = (b * NN + n0 + c0 + row) * DDIM + col;
      *(float4*)&Ks[row * DDIM + col] = *(const float4*)(K + g);
      *(float4*)&Vs[row * DDIM + col] = *(const float4*)(V + g);
    }
    __syncthreads();
#pragma unroll 5
    for (int nn2 = 0; nn2 < TN; ++nn2) {
      const int n = n0 + c0 + nn2;
      const float* kn = &Ks[nn2 * DDIM + h * 16];
      float kr[16];
#pragma unroll
      for (int c = 0; c < 4; ++c) {
        const float4 kv = *(const float4*)(kn + 4 * c);
        kr[4*c+0]=kv.x; kr[4*c+1]=kv.y; kr[4*c+2]=kv.z; kr[4*c+3]=kv.w;
      }
      float s0a=0.f, s0b=0.f, s1a=0.f, s1b=0.f;
#pragma unroll
      for (int i = 0; i < 8; ++i) {
        s0a = fmaf(q0[i],   kr[i],   s0a);
        s0b = fmaf(q0[i+8], kr[i+8], s0b);
        s1a = fmaf(q1[i],   kr[i],   s1a);
        s1b = fmaf(q1[i+8], kr[i+8], s1b);
      }
      const float e0 = __expf((s0a + s0b) + m0[n]);
      const float e1 = __expf((s1a + s1b) + m1[n]);
      l0 += e0; l1 += e1;
      const float* vn = &Vs[nn2 * DDIM + h * 16];
#pragma unroll
      for (int c = 0; c < 4; ++c) {
        const float4 vv = *(const float4*)(vn + 4 * c);
        a0[4*c+0] = fmaf(e0, vv.x, a0[4*c+0]);
        a0[4*c+1] = fmaf(e0, vv.y, a0[4*c+1]);
        a0[4*c+2] = fmaf(e0, vv.z, a0[4*c+2]);
        a0[4*c+3] = fmaf(e0, vv.w, a0[4*c+3]);
        a1[4*c+0] = fmaf(e1, vv.x, a1[4*c+0]);
        a1[4*c+1] = fmaf(e1, vv.y, a1[4*c+1]);
        a1[4*c+2] = fmaf(e1, vv.z, a1[4*c+2]);
        a1[4*c+3] = fmaf(e1, vv.w, a1[4*c+3]);
      }
    }
  }
  if (act) {
    const int base = (b * NSPL + split) * PP + p0;
    float* d0 = po + base * DDIM + h * 16;
#pragma unroll
    for (int c = 0; c < 4; ++c) {
      *(float4*)(d0 + 4*c)        = make_float4(a0[4*c+0],a0[4*c+1],a0[4*c+2],a0[4*c+3]);
      *(float4*)(d0 + DDIM + 4*c) = make_float4(a1[4*c+0],a1[4*c+1],a1[4*c+2],a1[4*c+3]);
    }
    lsum[base * HH + h]       = l0;
    lsum[(base + 1) * HH + h] = l1;
  }
}

// ---------------------------------------------------------------------------
// merge: mh_in[b][p][d] = (sum_s po) / (sum_s lsum[h(d)])
// ---------------------------------------------------------------------------
__global__ __launch_bounds__(256) void merge_kernel(
    const float* __restrict__ po, const float* __restrict__ lsum,
    float* __restrict__ mh_in)
{
  const int idx = blockIdx.x * 256 + threadIdx.x;   // over BB*PP*DDIM
  const int d = idx & 127;
  const int row = idx >> 7;        // b*PP + p
  const int b = row / PP;
  const int p = row - b * PP;
  const int h = d >> 4;
  float s = 0.f, lt = 0.f;
#pragma unroll
  for (int sp = 0; sp < NSPL; ++sp) {
    const int base = (b * NSPL + sp) * PP + p;
    s  += po[base * DDIM + d];
    lt += lsum[base * HH + h];
  }
  mh_in[idx] = s / lt;
}

// ---------------------------------------------------------------------------
// score2 + bias + mask + exp  (softmax numerator; scores bounded by 10.2 so
// no max subtraction needed). Writes e to out, chunk-partial sums to ssum.
// grid = BB*4chunks*2phalf = 512, block = 256 (thread = one n; t<250 active)
// ---------------------------------------------------------------------------
__global__ __launch_bounds__(256) void score2_kernel(
    const float* __restrict__ enc, const float* __restrict__ mh,
    const float* __restrict__ mask, const float* __restrict__ bias_table,
    const int* __restrict__ group_ids, const int* __restrict__ cur_min,
    float* __restrict__ out, float* __restrict__ ssum)
{
  const int b = blockIdx.x >> 3;
  const int chunk = (blockIdx.x >> 1) & 3;
  const int phalf = blockIdx.x & 1;
  const int t = threadIdx.x;
  const int nn = chunk * 250 + t;
  const bool act = (t < 250);
  const int nc = act ? nn : chunk * 250;

  float er[DDIM];
  {
    const float* ep = enc + (b * NN + nc) * DDIM;
#pragma unroll
    for (int c = 0; c < 32; ++c) {
      const float4 v4 = *(const float4*)(ep + 4 * c);
      er[4*c+0]=v4.x; er[4*c+1]=v4.y; er[4*c+2]=v4.z; er[4*c+3]=v4.w;
    }
  }
  const int gid = group_ids[b * NN + nc];
  const float t0 = bias_table[0], t1 = bias_table[1], t2 = bias_table[2],
              t3 = bias_table[3], t4 = bias_table[4];

  __shared__ float psum[50];
  if (t < 50) psum[t] = 0.f;
  __syncthreads();

  const float inv_sqrt_emb = 0.08838834764831845f;  // 1/sqrt(128)
  const int p0 = phalf * 50;
  for (int pi = 0; pi < 50; ++pi) {
    const int p = p0 + pi;
    const float* mhp = mh + (b * PP + p) * DDIM;
    float d0=0.f, d1=0.f, d2=0.f, d3=0.f;
#pragma unroll
    for (int d = 0; d < DDIM; d += 4) {
      d0 = fmaf(er[d+0], mhp[d+0], d0);
      d1 = fmaf(er[d+1], mhp[d+1], d1);
      d2 = fmaf(er[d+2], mhp[d+2], d2);
      d3 = fmaf(er[d+3], mhp[d+3], d3);
    }
    const float dot = (d0 + d1) + (d2 + d3);
    // 10*tanh(x) = 10 - 20/(exp(2x)+1); saturates gracefully at +-10
    const float ex = __expf(dot * inv_sqrt_emb * 2.0f);
    const float sc = 10.0f - 20.0f / (ex + 1.0f);
    const int cmp = cur_min[b * PP + p];
    int delta = gid - cmp;
    delta = delta < 0 ? 0 : (delta > 4 ? 4 : delta);
    const float pb = (delta == 0) ? t0 : (delta == 1) ? t1 : (delta == 2) ? t2
                   : (delta == 3) ? t3 : t4;
    const float m = mask[(b * PP + p) * NN + nc];
    const float e = act ? __expf(sc + pb + m) : 0.0f;   // exp(-inf)=0 handles mask
    if (act) out[(b * PP + p) * NN + nn] = e;
    float wsum = e;
#pragma unroll
    for (int off = 1; off < 64; off <<= 1) wsum += __shfl_xor(wsum, off, 64);
    if ((t & 63) == 0) atomicAdd(&psum[pi], wsum);
  }
  __syncthreads();
  if (t < 50) ssum[(b * PP + p0 + t) * 4 + chunk] = psum[t];
}

// ---------------------------------------------------------------------------
// normalize: out[row][n] /= sum of 4 chunk partials
// ---------------------------------------------------------------------------
__global__ __launch_bounds__(256) void norm_kernel(
    const float* __restrict__ ssum, float* __restrict__ out)
{
  const int row = blockIdx.x;   // b*PP + p
  const float s = ssum[row*4+0] + ssum[row*4+1] + ssum[row*4+2] + ssum[row*4+3];
  const float inv = 1.0f / s;
#pragma unroll
  for (int i = 0; i < 4; ++i) {
    const int c = i * 256 + (int)threadIdx.x;
    if (c < NN) out[row * NN + c] *= inv;
  }
}

// ---------------------------------------------------------------------------
extern "C" void kernel_launch(void* const* d_in, const int* in_sizes, int n_in,
                              void* d_out, int out_size, void* d_ws, size_t ws_size,
                              hipStream_t stream)
{
  (void)in_sizes; (void)n_in; (void)out_size; (void)ws_size;
  const float* enc_nodes  = (const float*)d_in[0];
  const float* enc_q1     = (const float*)d_in[1];
  const float* enc_last   = (const float*)d_in[2];
  const float* ninf       = (const float*)d_in[3];
  const float* Wq_first   = (const float*)d_in[4];
  const float* Wq_last    = (const float*)d_in[5];
  const float* Wk         = (const float*)d_in[6];
  const float* Wv         = (const float*)d_in[7];
  const float* W_comb     = (const float*)d_in[8];
  const float* b_comb     = (const float*)d_in[9];
  const float* bias_table = (const float*)d_in[10];
  const int*   group_ids  = (const int*)d_in[11];
  const int*   cur_min    = (const int*)d_in[12];
  float* out = (float*)d_out;
  float* ws  = (float*)d_ws;

  float* Qw = ws;                    //   819200 floats (reused as mh_in after attn)
  float* Kw = Qw + 819200;           //  8192000
  float* Vw = Kw + 8192000;          //  8192000
  float* po = Vw + 8192000;          //  6553600  (BB*NSPL*PP*DDIM)
  float* ls = po + 6553600;          //   409600  (BB*NSPL*PP*HH)
  float* mh = ls + 409600;           //   819200
  float* sm = mh + 819200;           //    25600  (BB*PP*4)

  // Q = (q1@Wq_first + last@Wq_last) * 0.25  (fold 1/sqrt(QD))
  proj_q2_kernel<<<400, 256, 0, stream>>>(enc_q1, enc_last, Wq_first, Wq_last,
                                          Qw, BB*PP, 0.25f);
  // K, V projections fused (one pass over enc_nodes)
  proj_kv_kernel<<<2000, 256, 0, stream>>>(enc_nodes, Wk, Wv, Kw, Vw, BB*NN);
  // attention partials (LDS-staged K/V)
  attn_kernel<<<BB*NSPL, 448, 0, stream>>>(Qw, Kw, Vw, ninf, po, ls);
  // merge partials -> mh_in (reuses Qw)
  merge_kernel<<<3200, 256, 0, stream>>>(po, ls, Qw);
  // combine: mh = mh_in @ W_comb + b_comb
  proj_bias_kernel<<<400, 256, 0, stream>>>(Qw, W_comb, b_comb, mh, BB*PP);
  // final scores + exp + partial sums
  score2_kernel<<<BB*8, 256, 0, stream>>>(enc_nodes, mh, ninf, bias_table,
                                          group_ids, cur_min, out, sm);
  // normalize
  norm_kernel<<<BB*PP, 256, 0, stream>>>(sm, out);
}